// Round 1
// baseline (2317.488 us; speedup 1.0000x reference)
//
#include <hip/hip_runtime.h>
#include <hip/hip_bf16.h>
#include <stdint.h>

// GroupLinear: out[l,o] = sum_{g,i,j} x1[l,g*64+i]*x2[l,g*64+j]*W[o,(g*64+i)*64+j] + b[o]
// == GEMM C = Z * W^T, Z[l,k]=x1*x2 built on the fly (K-slab of 64 = fixed (g,i), j contiguous).

#define L_DIM 2048
#define H_DIM 1024
#define O_DIM 1024
#define BSZ   64
#define KDIM  65536

constexpr int BM = 128, BN = 128, BK = 64;
constexpr int SPLITK = 4;
constexpr int KITERS = (KDIM / BK) / SPLITK;  // 256 K-iters per block
constexpr int LDSS = 88;   // shorts per LDS row: 64 + 24 pad -> 176B (16B aligned, 2-way bank conflicts only)

typedef __attribute__((ext_vector_type(8))) short bf16x8;
typedef __attribute__((ext_vector_type(4))) float f32x4;

__device__ __forceinline__ unsigned short f2b(float x) {
    __hip_bfloat16 h = __float2bfloat16(x);
    return __builtin_bit_cast(unsigned short, h);
}

// out[l][o] = bias[o]  (atomic-accumulation base; harness poisons d_out)
__global__ __launch_bounds__(256) void gl_init(const float* __restrict__ bias,
                                               float* __restrict__ out) {
    int idx = blockIdx.x * 256 + threadIdx.x;          // float4 index
    int o = (idx * 4) & (O_DIM - 1);
    f32x4 bv = *reinterpret_cast<const f32x4*>(bias + o);
    reinterpret_cast<f32x4*>(out)[idx] = bv;
}

__global__ __launch_bounds__(256, 2) void gl_gemm(const float* __restrict__ x1,
                                                  const float* __restrict__ x2,
                                                  const float* __restrict__ W,
                                                  float* __restrict__ out) {
    __shared__ unsigned short Ab[BM * LDSS];
    __shared__ unsigned short Bb[BN * LDSS];

    const int tid  = threadIdx.x;
    const int lane = tid & 63;
    const int wid  = tid >> 6;
    const int wm   = (wid >> 1) * 64;   // wave row offset in tile
    const int wn   = (wid & 1) * 64;    // wave col offset in tile
    const int quad = lane >> 4;
    const int l16  = lane & 15;
    const int m0   = blockIdx.y * BM;
    const int n0   = blockIdx.x * BN;
    const int kk0  = blockIdx.z * KITERS;

    const int srow = tid >> 4;          // staging row base (+16 per c)
    const int scol = (tid & 15) * 4;    // staging float col (0..60)

    f32x4 acc[4][4] = {};

    for (int kk = kk0; kk < kk0 + KITERS; ++kk) {
        const int g = kk >> 6;          // 64 iters per g
        const int i = kk & 63;

        __syncthreads();                // previous iter's fragment reads done

        // A tile: z[r][j] = x1[m0+r][g*64+i] * x2[m0+r][g*64+j], j = 0..63
        #pragma unroll
        for (int c = 0; c < 8; ++c) {
            const int r = srow + c * 16;
            const float x1v = x1[(m0 + r) * H_DIM + g * BSZ + i];
            const f32x4 v = *reinterpret_cast<const f32x4*>(
                &x2[(m0 + r) * H_DIM + g * BSZ + scol]);
            ushort4 h;
            h.x = f2b(v.x * x1v); h.y = f2b(v.y * x1v);
            h.z = f2b(v.z * x1v); h.w = f2b(v.w * x1v);
            *reinterpret_cast<ushort4*>(&Ab[r * LDSS + scol]) = h;
        }
        // B tile: W[n0+r][kk*64 + col] (row-major [O, K] => B^T layout, NT GEMM)
        #pragma unroll
        for (int c = 0; c < 8; ++c) {
            const int r = srow + c * 16;
            const f32x4 v = *reinterpret_cast<const f32x4*>(
                &W[(size_t)(n0 + r) * KDIM + (size_t)kk * BK + scol]);
            ushort4 h;
            h.x = f2b(v.x); h.y = f2b(v.y); h.z = f2b(v.z); h.w = f2b(v.w);
            *reinterpret_cast<ushort4*>(&Bb[r * LDSS + scol]) = h;
        }
        __syncthreads();                // staging visible

        #pragma unroll
        for (int ks = 0; ks < 2; ++ks) {
            const int koff = ks * 32 + quad * 8;   // A[m][k=quad*8+j] layout
            bf16x8 af[4], bfr[4];
            #pragma unroll
            for (int mt = 0; mt < 4; ++mt)
                af[mt] = *reinterpret_cast<const bf16x8*>(
                    &Ab[(wm + mt * 16 + l16) * LDSS + koff]);
            #pragma unroll
            for (int nt = 0; nt < 4; ++nt)
                bfr[nt] = *reinterpret_cast<const bf16x8*>(
                    &Bb[(wn + nt * 16 + l16) * LDSS + koff]);
            #pragma unroll
            for (int mt = 0; mt < 4; ++mt)
                #pragma unroll
                for (int nt = 0; nt < 4; ++nt)
                    acc[mt][nt] = __builtin_amdgcn_mfma_f32_16x16x32_bf16(
                        af[mt], bfr[nt], acc[mt][nt], 0, 0, 0);
        }
    }

    // Epilogue: accumulate split-K partials. C/D layout: row(m)=quad*4+reg, col(n)=lane&15.
    #pragma unroll
    for (int mt = 0; mt < 4; ++mt) {
        const int mb = m0 + wm + mt * 16 + quad * 4;
        #pragma unroll
        for (int nt = 0; nt < 4; ++nt) {
            const int n = n0 + wn + nt * 16 + l16;
            #pragma unroll
            for (int r = 0; r < 4; ++r)
                unsafeAtomicAdd(&out[(mb + r) * O_DIM + n], acc[mt][nt][r]);
        }
    }
}

extern "C" void kernel_launch(void* const* d_in, const int* in_sizes, int n_in,
                              void* d_out, int out_size, void* d_ws, size_t ws_size,
                              hipStream_t stream) {
    const float* x1 = (const float*)d_in[0];
    const float* x2 = (const float*)d_in[1];
    const float* W  = (const float*)d_in[2];
    const float* b  = (const float*)d_in[3];
    float* out = (float*)d_out;

    // init out with bias (d_out is poisoned before every timed launch)
    gl_init<<<dim3((L_DIM * O_DIM / 4) / 256), dim3(256), 0, stream>>>(b, out);

    dim3 grid(O_DIM / BN, L_DIM / BM, SPLITK);   // 8 x 16 x 4 = 512 blocks, ~2/CU
    gl_gemm<<<grid, dim3(256), 0, stream>>>(x1, x2, W, out);
}

// Round 2
// 1109.577 us; speedup vs baseline: 2.0886x; 2.0886x over previous
//
#include <hip/hip_runtime.h>
#include <hip/hip_bf16.h>
#include <stdint.h>

// GroupLinear: out[l,o] = sum_{g,i,j} x1[l,g*64+i]*x2[l,g*64+j]*W[o,(g*64+i)*64+j] + b[o]
// == GEMM C = Z * W^T, Z[l,k]=x1*x2 built on the fly (K-slab of 64 = fixed (g,i), j contiguous).
// Round 2: pre-convert W->bf16 in d_ws; B staged via async global_load_lds (16B) with
// XOR-swizzled LDS chunks; split-K=8 -> 4 blocks/CU.

#define L_DIM 2048
#define H_DIM 1024
#define O_DIM 1024
#define BSZ   64
#define KDIM  65536

constexpr int BM = 128, BN = 128, BK = 64;
constexpr int SPLITK = 8;
constexpr int KITERS = (KDIM / BK) / SPLITK;  // 128 K-iters per block
constexpr int LDSS = 88;   // A-tile LDS row stride in shorts (64 + 24 pad)

typedef __attribute__((ext_vector_type(8))) short bf16x8;
typedef __attribute__((ext_vector_type(8))) unsigned short u16x8;
typedef __attribute__((ext_vector_type(4))) float f32x4;

__device__ __forceinline__ unsigned short f2b(float x) {
    __hip_bfloat16 h = __float2bfloat16(x);
    return __builtin_bit_cast(unsigned short, h);
}

// ---- W fp32 -> bf16 into workspace (8 floats / thread, 16B stores) ----
__global__ __launch_bounds__(256) void w_convert(const float* __restrict__ W,
                                                 unsigned short* __restrict__ Wb) {
    size_t idx = (size_t)blockIdx.x * 256 + threadIdx.x;   // index of 8-float chunk
    const f32x4* src = reinterpret_cast<const f32x4*>(W);
    f32x4 a = src[idx * 2], b = src[idx * 2 + 1];
    u16x8 h;
    h[0] = f2b(a.x); h[1] = f2b(a.y); h[2] = f2b(a.z); h[3] = f2b(a.w);
    h[4] = f2b(b.x); h[5] = f2b(b.y); h[6] = f2b(b.z); h[7] = f2b(b.w);
    reinterpret_cast<u16x8*>(Wb)[idx] = h;
}

// ---- out[l][o] = bias[o] (atomic-accumulation base) ----
__global__ __launch_bounds__(256) void gl_init(const float* __restrict__ bias,
                                               float* __restrict__ out) {
    int idx = blockIdx.x * 256 + threadIdx.x;          // float4 index
    int o = (idx * 4) & (O_DIM - 1);
    f32x4 bv = *reinterpret_cast<const f32x4*>(bias + o);
    reinterpret_cast<f32x4*>(out)[idx] = bv;
}

// ---- main GEMM: A (z-tile) via register cvt -> padded LDS; B via global_load_lds ----
__global__ __launch_bounds__(256, 4) void gl_gemm(const float* __restrict__ x1,
                                                  const float* __restrict__ x2,
                                                  const unsigned short* __restrict__ Wb,
                                                  float* __restrict__ out) {
    __shared__ unsigned short Ab[BM * LDSS];    // 22.5 KB, padded rows
    __shared__ unsigned short Bb[BN * BK];      // 16 KB, unpadded, XOR-swizzled chunks

    const int tid  = threadIdx.x;
    const int lane = tid & 63;
    const int wid  = tid >> 6;
    const int wm   = (wid >> 1) * 64;   // wave row offset in tile
    const int wn   = (wid & 1) * 64;    // wave col offset in tile
    const int quad = lane >> 4;
    const int l16  = lane & 15;
    const int m0   = blockIdx.y * BM;
    const int n0   = blockIdx.x * BN;
    const int kk0  = blockIdx.z * KITERS;

    const int srow = tid >> 4;          // A staging row base (+16 per c)
    const int scol = (tid & 15) * 4;    // A staging float col (0..60)

    // B staging: per round p (0..3), this lane owns row r = p*32 + wid*8 + (lane>>3),
    // chunk c = lane&7 (16B). LDS slot (r,c) receives global chunk c ^ (r&7).
    const int brow_in = lane >> 3;              // 0..7
    const int bc      = lane & 7;               // chunk 0..7
    const int bcs     = bc ^ brow_in;           // swizzled source chunk (r&7 == brow_in)
    // per-lane global base for round 0 (advance by p*32 rows / kk*64 elems)
    const unsigned short* gB0 =
        Wb + (size_t)(n0 + wid * 8 + brow_in) * KDIM + (size_t)kk0 * BK + bcs * 8;
    unsigned short* const lB0 = &Bb[(wid * 8) * BK];   // wave-uniform LDS base, round 0

    f32x4 acc[4][4] = {};

    for (int it = 0; it < KITERS; ++it) {
        const int kk = kk0 + it;
        const int g = kk >> 6;          // 64 iters per g
        const int i = kk & 63;

        __syncthreads();                // previous iter's fragment reads done

        // --- B tile: async global->LDS, 4 rounds x (256 lanes x 16B) = 16 KB ---
        #pragma unroll
        for (int p = 0; p < 4; ++p) {
            const unsigned short* gp = gB0 + (size_t)it * BK + (size_t)p * 32 * KDIM;
            unsigned short* lp = lB0 + p * 32 * BK;
            __builtin_amdgcn_global_load_lds(
                (const __attribute__((address_space(1))) void*)gp,
                (__attribute__((address_space(3))) void*)lp, 16, 0, 0);
        }

        // --- A tile: z[r][j] = x1[m0+r][g*64+i] * x2[m0+r][g*64+j] (overlaps B loads) ---
        #pragma unroll
        for (int c = 0; c < 8; ++c) {
            const int r = srow + c * 16;
            const float x1v = x1[(m0 + r) * H_DIM + g * BSZ + i];
            const f32x4 v = *reinterpret_cast<const f32x4*>(
                &x2[(m0 + r) * H_DIM + g * BSZ + scol]);
            ushort4 h;
            h.x = f2b(v.x * x1v); h.y = f2b(v.y * x1v);
            h.z = f2b(v.z * x1v); h.w = f2b(v.w * x1v);
            *reinterpret_cast<ushort4*>(&Ab[r * LDSS + scol]) = h;
        }
        __syncthreads();                // drains vmcnt (global_load_lds) + lgkm

        #pragma unroll
        for (int ks = 0; ks < 2; ++ks) {
            const int koff = ks * 32 + quad * 8;   // A[m][k=quad*8+j] layout
            bf16x8 af[4], bfr[4];
            #pragma unroll
            for (int mt = 0; mt < 4; ++mt)
                af[mt] = *reinterpret_cast<const bf16x8*>(
                    &Ab[(wm + mt * 16 + l16) * LDSS + koff]);
            const int q = ks * 4 + quad;           // B chunk index
            const int qs = (q ^ (l16 & 7)) * 8;    // unswizzle
            #pragma unroll
            for (int nt = 0; nt < 4; ++nt)
                bfr[nt] = *reinterpret_cast<const bf16x8*>(
                    &Bb[(wn + nt * 16 + l16) * BK + qs]);
            #pragma unroll
            for (int mt = 0; mt < 4; ++mt)
                #pragma unroll
                for (int nt = 0; nt < 4; ++nt)
                    acc[mt][nt] = __builtin_amdgcn_mfma_f32_16x16x32_bf16(
                        af[mt], bfr[nt], acc[mt][nt], 0, 0, 0);
        }
    }

    // Epilogue: accumulate split-K partials. C/D layout: row(m)=quad*4+reg, col(n)=lane&15.
    #pragma unroll
    for (int mt = 0; mt < 4; ++mt) {
        const int mb = m0 + wm + mt * 16 + quad * 4;
        #pragma unroll
        for (int nt = 0; nt < 4; ++nt) {
            const int n = n0 + wn + nt * 16 + l16;
            #pragma unroll
            for (int r = 0; r < 4; ++r)
                unsafeAtomicAdd(&out[(mb + r) * O_DIM + n], acc[mt][nt][r]);
        }
    }
}

// ---- fallback (round-1 kernel) if workspace is too small for bf16 W ----
__global__ __launch_bounds__(256, 2) void gl_gemm_fb(const float* __restrict__ x1,
                                                     const float* __restrict__ x2,
                                                     const float* __restrict__ W,
                                                     float* __restrict__ out) {
    __shared__ unsigned short Ab[BM * LDSS];
    __shared__ unsigned short Bb2[BN * LDSS];

    const int tid  = threadIdx.x;
    const int lane = tid & 63;
    const int wid  = tid >> 6;
    const int wm   = (wid >> 1) * 64;
    const int wn   = (wid & 1) * 64;
    const int quad = lane >> 4;
    const int l16  = lane & 15;
    const int m0   = blockIdx.y * BM;
    const int n0   = blockIdx.x * BN;
    const int kk0  = blockIdx.z * (KDIM / BK / 4);

    const int srow = tid >> 4;
    const int scol = (tid & 15) * 4;

    f32x4 acc[4][4] = {};

    for (int kk = kk0; kk < kk0 + (KDIM / BK / 4); ++kk) {
        const int g = kk >> 6;
        const int i = kk & 63;
        __syncthreads();
        #pragma unroll
        for (int c = 0; c < 8; ++c) {
            const int r = srow + c * 16;
            const float x1v = x1[(m0 + r) * H_DIM + g * BSZ + i];
            const f32x4 v = *reinterpret_cast<const f32x4*>(
                &x2[(m0 + r) * H_DIM + g * BSZ + scol]);
            ushort4 h;
            h.x = f2b(v.x * x1v); h.y = f2b(v.y * x1v);
            h.z = f2b(v.z * x1v); h.w = f2b(v.w * x1v);
            *reinterpret_cast<ushort4*>(&Ab[r * LDSS + scol]) = h;
        }
        #pragma unroll
        for (int c = 0; c < 8; ++c) {
            const int r = srow + c * 16;
            const f32x4 v = *reinterpret_cast<const f32x4*>(
                &W[(size_t)(n0 + r) * KDIM + (size_t)kk * BK + scol]);
            ushort4 h;
            h.x = f2b(v.x); h.y = f2b(v.y); h.z = f2b(v.z); h.w = f2b(v.w);
            *reinterpret_cast<ushort4*>(&Bb2[r * LDSS + scol]) = h;
        }
        __syncthreads();
        #pragma unroll
        for (int ks = 0; ks < 2; ++ks) {
            const int koff = ks * 32 + quad * 8;
            bf16x8 af[4], bfr[4];
            #pragma unroll
            for (int mt = 0; mt < 4; ++mt)
                af[mt] = *reinterpret_cast<const bf16x8*>(
                    &Ab[(wm + mt * 16 + l16) * LDSS + koff]);
            #pragma unroll
            for (int nt = 0; nt < 4; ++nt)
                bfr[nt] = *reinterpret_cast<const bf16x8*>(
                    &Bb2[(wn + nt * 16 + l16) * LDSS + koff]);
            #pragma unroll
            for (int mt = 0; mt < 4; ++mt)
                #pragma unroll
                for (int nt = 0; nt < 4; ++nt)
                    acc[mt][nt] = __builtin_amdgcn_mfma_f32_16x16x32_bf16(
                        af[mt], bfr[nt], acc[mt][nt], 0, 0, 0);
        }
    }
    #pragma unroll
    for (int mt = 0; mt < 4; ++mt) {
        const int mb = m0 + wm + mt * 16 + quad * 4;
        #pragma unroll
        for (int nt = 0; nt < 4; ++nt) {
            const int n = n0 + wn + nt * 16 + l16;
            #pragma unroll
            for (int r = 0; r < 4; ++r)
                unsafeAtomicAdd(&out[(mb + r) * O_DIM + n], acc[mt][nt][r]);
        }
    }
}

extern "C" void kernel_launch(void* const* d_in, const int* in_sizes, int n_in,
                              void* d_out, int out_size, void* d_ws, size_t ws_size,
                              hipStream_t stream) {
    const float* x1 = (const float*)d_in[0];
    const float* x2 = (const float*)d_in[1];
    const float* W  = (const float*)d_in[2];
    const float* b  = (const float*)d_in[3];
    float* out = (float*)d_out;

    const size_t w_bf16_bytes = (size_t)O_DIM * KDIM * sizeof(unsigned short); // 134 MB

    // init out with bias (d_out is poisoned before every timed launch)
    gl_init<<<dim3((L_DIM * O_DIM / 4) / 256), dim3(256), 0, stream>>>(b, out);

    if (ws_size >= w_bf16_bytes) {
        unsigned short* Wb = (unsigned short*)d_ws;
        // convert W once per launch: 67.1M floats, 8 per thread
        w_convert<<<dim3((size_t)O_DIM * KDIM / 8 / 256), dim3(256), 0, stream>>>(W, Wb);
        dim3 grid(O_DIM / BN, L_DIM / BM, SPLITK);   // 8 x 16 x 8 = 1024 blocks, 4/CU
        gl_gemm<<<grid, dim3(256), 0, stream>>>(x1, x2, Wb, out);
    } else {
        dim3 grid(O_DIM / BN, L_DIM / BM, 4);
        gl_gemm_fb<<<grid, dim3(256), 0, stream>>>(x1, x2, W, out);
    }
}